// Round 2
// baseline (554.279 us; speedup 1.0000x reference)
//
#include <hip/hip_runtime.h>
#include <hip/hip_bf16.h>

#define BT 16384   // B*T = 32*512
#define DIM 768
#define NH 12
#define DFF 3072

typedef __attribute__((ext_vector_type(8))) short short8;
typedef __attribute__((ext_vector_type(8))) unsigned short ushort8;
typedef __attribute__((ext_vector_type(4))) float floatx4;

using bf16 = __hip_bfloat16;

static __device__ __forceinline__ float b2f(bf16 v) { return __bfloat162float(v); }
static __device__ __forceinline__ bf16 f2b(float v) { return __float2bfloat16(v); }
static __device__ __forceinline__ void st_o(bf16* p, float v) { *p = __float2bfloat16(v); }
static __device__ __forceinline__ void st_o(float* p, float v) { *p = v; }

// ---- weight pack: fp32 -> bf16, all B matrices stored TRANSPOSED [N][K] (k-contiguous) ----
// wqkv [216][768]; wo_t [768][96] (k=72..95 zeroed); w1t [3072][768]; w2t [768][3072]
__global__ __launch_bounds__(256) void pack_kernel(
    const float* __restrict__ Wq, const float* __restrict__ Wk, const float* __restrict__ Wv,
    const float* __restrict__ Wo, const float* __restrict__ W1, const float* __restrict__ W2,
    bf16* __restrict__ wqkv, bf16* __restrict__ wo_t,
    bf16* __restrict__ w1t, bf16* __restrict__ w2t)
{
    int i = blockIdx.x * 256 + threadIdx.x;
    const int S0 = 216 * 768, S1 = 768 * 96, S2 = 3072 * 768, S3 = 768 * 3072;
    if (i < S0) {
        int c = i / 768, dd = i % 768;           // row c (output col), k = dd
        int sel = c / 72, cc = c % 72, h = cc / 6, e = cc % 6;
        const float* W = (sel == 0) ? Wq : (sel == 1) ? Wk : Wv;   // (H, D, E)
        wqkv[i] = f2b(W[((size_t)h * 768 + dd) * 6 + e]);
    } else if ((i -= S0) < S1) {
        int n = i / 96, r = i % 96;              // Wo is (72, 768): [r][n]
        wo_t[i] = f2b(r < 72 ? Wo[r * 768 + n] : 0.f);
    } else if ((i -= S1) < S2) {
        int n = i / 768, k = i % 768;            // W1 is (768, 3072): [k][n]
        w1t[i] = f2b(W1[(size_t)k * 3072 + n]);
    } else if ((i -= S2) < S3) {
        int n = i / 3072, k = i % 3072;          // W2 is (3072, 768): [k][n]
        w2t[i] = f2b(W2[(size_t)k * 768 + n]);
    }
}

// ---------------- LayerNorm: one block per row of 768, fp32 in, bf16 out ----------------
__global__ __launch_bounds__(256) void ln_kernel(
    const float* __restrict__ x, const float* __restrict__ g, const float* __restrict__ be,
    bf16* __restrict__ out)
{
    int row = blockIdx.x;
    int tid = threadIdx.x;
    const float* xr = x + (size_t)row * DIM;
    float v[3], s = 0.f, s2 = 0.f;
#pragma unroll
    for (int i = 0; i < 3; i++) {
        float t = xr[tid + i * 256];
        v[i] = t; s += t; s2 += t * t;
    }
#pragma unroll
    for (int off = 32; off; off >>= 1) {
        s += __shfl_down(s, off);
        s2 += __shfl_down(s2, off);
    }
    __shared__ float red[8];
    int wv = tid >> 6, ln = tid & 63;
    if (ln == 0) { red[wv] = s; red[4 + wv] = s2; }
    __syncthreads();
    float ts = red[0] + red[1] + red[2] + red[3];
    float ts2 = red[4] + red[5] + red[6] + red[7];
    float mean = ts * (1.f / 768.f);
    float var = ts2 * (1.f / 768.f) - mean * mean;
    float rstd = rsqrtf(var + 1e-5f);
    bf16* orow = out + (size_t)row * DIM;
#pragma unroll
    for (int i = 0; i < 3; i++) {
        int dcol = tid + i * 256;
        orow[dcol] = f2b((v[i] - mean) * rstd * g[dcol] + be[dcol]);
    }
}

// ---------------- MFMA bf16 GEMM: C[M,N] = A[M,K] @ Bt[N,K]^T (+bias)(+res)(+relu) ----------------
// 128x128 tile, BK=32, 256 threads (4 waves, 2x2 of 64x64), 16x16x32 bf16 MFMA.
// A frag: lane holds A[m=lane&15][k=quad*8+j]; B frag: B[k=quad*8+j][n=lane&15] = Bt[n][k];
// C/D: col=lane&15, row=quad*4+reg.  Requires M%128==0 and K%32==0 (true for all calls).
template <bool RELU, bool BIAS, bool RES, typename OutT>
__global__ __launch_bounds__(256) void gemm_kernel(
    const bf16* __restrict__ A, const bf16* __restrict__ Bt,
    const float* __restrict__ bias, const float* __restrict__ res,
    OutT* __restrict__ C, int M, int N, int K)
{
    __shared__ __align__(16) bf16 lA[128 * 40];  // [row][k], stride 40 (2-way bank alias = free)
    __shared__ __align__(16) bf16 lB[128 * 40];  // [n][k], stride 40
    const int tid = threadIdx.x;
    const int bm = blockIdx.x * 128;
    const int bn = blockIdx.y * 128;
    const int wave = tid >> 6, lane = tid & 63;
    const int wm = (wave >> 1) * 64, wn = (wave & 1) * 64;
    const int quad = lane >> 4, l16 = lane & 15;

    floatx4 acc[4][4] = {};
    const unsigned short* Au = (const unsigned short*)A;
    const unsigned short* Bu = (const unsigned short*)Bt;

    const int row0 = tid >> 2, kc0 = (tid & 3) * 8;  // 128 rows x 32 k in two passes of 64 rows... 
    // actually: c = tid + it*256 -> row=c>>2 in [0,128), kc=(c&3)*8 in {0,8,16,24}

    for (int k0 = 0; k0 < K; k0 += 32) {
#pragma unroll
        for (int it = 0; it < 2; it++) {
            int c = tid + it * 256;
            int row = c >> 2, kc = (c & 3) * 8;
            *(ushort8*)(lA + row * 40 + kc) =
                *(const ushort8*)(Au + (size_t)(bm + row) * K + k0 + kc);
        }
#pragma unroll
        for (int it = 0; it < 2; it++) {
            int c = tid + it * 256;
            int n = c >> 2, kc = (c & 3) * 8;
            ushort8 vb = {0, 0, 0, 0, 0, 0, 0, 0};
            if (bn + n < N)
                vb = *(const ushort8*)(Bu + (size_t)(bn + n) * K + k0 + kc);
            *(ushort8*)(lB + n * 40 + kc) = vb;
        }
        __syncthreads();
        short8 af[4], bfr[4];
#pragma unroll
        for (int mt = 0; mt < 4; mt++)
            af[mt] = *(const short8*)(lA + (wm + mt * 16 + l16) * 40 + quad * 8);
#pragma unroll
        for (int nt = 0; nt < 4; nt++)
            bfr[nt] = *(const short8*)(lB + (wn + nt * 16 + l16) * 40 + quad * 8);
#pragma unroll
        for (int mt = 0; mt < 4; mt++)
#pragma unroll
            for (int nt = 0; nt < 4; nt++)
                acc[mt][nt] = __builtin_amdgcn_mfma_f32_16x16x32_bf16(af[mt], bfr[nt], acc[mt][nt], 0, 0, 0);
        __syncthreads();
    }

#pragma unroll
    for (int mt = 0; mt < 4; mt++) {
#pragma unroll
        for (int nt = 0; nt < 4; nt++) {
            int gc = bn + wn + nt * 16 + l16;
            if (gc < N) {
#pragma unroll
                for (int r = 0; r < 4; r++) {
                    int gr = bm + wm + mt * 16 + quad * 4 + r;
                    float v0 = acc[mt][nt][r];
                    if constexpr (BIAS) v0 += bias[gc];
                    if constexpr (RES) v0 += res[(size_t)gr * N + gc];
                    if constexpr (RELU) v0 = fmaxf(v0, 0.f);
                    st_o(C + (size_t)gr * N + gc, v0);
                }
            }
        }
    }
}

// ---------------- causal attention, online softmax; qkv layout [BT][216]: q|k|v each 72 cols ----------------
__global__ __launch_bounds__(256) void attn_kernel(const bf16* __restrict__ qkv, bf16* __restrict__ o_pad)
{
    int blk = blockIdx.x;
    int half = blk & 1;
    int bh = blk >> 1;
    int b = bh / NH, h = bh % NH;
    int t0 = half * 256;
    int smax = t0 + 256;  // keys needed: s <= t0+255

    __shared__ float ks[512 * 6];
    __shared__ float vs[512 * 6];
    const bf16* base = qkv + (size_t)b * 512 * 216;
    for (int i = threadIdx.x; i < smax * 6; i += 256) {
        int s = i / 6, e = i % 6;
        ks[i] = b2f(base[s * 216 + 72 + h * 6 + e]);
        vs[i] = b2f(base[s * 216 + 144 + h * 6 + e]);
    }
    __syncthreads();

    int t = t0 + threadIdx.x;
    float q0 = b2f(base[t * 216 + h * 6 + 0]);
    float q1 = b2f(base[t * 216 + h * 6 + 1]);
    float q2 = b2f(base[t * 216 + h * 6 + 2]);
    float q3 = b2f(base[t * 216 + h * 6 + 3]);
    float q4 = b2f(base[t * 216 + h * 6 + 4]);
    float q5 = b2f(base[t * 216 + h * 6 + 5]);

    const float scale = 0.4082482904638630f;  // 1/sqrt(6)
    float m = -1e30f, l = 0.f;
    float o0 = 0, o1 = 0, o2 = 0, o3 = 0, o4 = 0, o5 = 0;
    for (int s = 0; s <= t; s++) {
        const float* kk = &ks[s * 6];
        float sc = (q0 * kk[0] + q1 * kk[1] + q2 * kk[2] + q3 * kk[3] + q4 * kk[4] + q5 * kk[5]) * scale;
        float nm = fmaxf(m, sc);
        float alpha = __expf(m - nm);
        float p = __expf(sc - nm);
        l = l * alpha + p;
        const float* vv = &vs[s * 6];
        o0 = o0 * alpha + p * vv[0];
        o1 = o1 * alpha + p * vv[1];
        o2 = o2 * alpha + p * vv[2];
        o3 = o3 * alpha + p * vv[3];
        o4 = o4 * alpha + p * vv[4];
        o5 = o5 * alpha + p * vv[5];
        m = nm;
    }
    float inv = 1.f / l;
    bf16* orow = o_pad + (size_t)(b * 512 + t) * 96 + h * 6;
    orow[0] = f2b(o0 * inv);
    orow[1] = f2b(o1 * inv);
    orow[2] = f2b(o2 * inv);
    orow[3] = f2b(o3 * inv);
    orow[4] = f2b(o4 * inv);
    orow[5] = f2b(o5 * inv);
    // cols 72..95 of o_pad stay poison (finite bf16 0xAAAA): matching wo_t k-cols are zero -> contributes 0.
}

extern "C" void kernel_launch(void* const* d_in, const int* in_sizes, int n_in,
                              void* d_out, int out_size, void* d_ws, size_t ws_size,
                              hipStream_t stream)
{
    const float* x   = (const float*)d_in[0];
    const float* Wq  = (const float*)d_in[1];
    const float* Wk  = (const float*)d_in[2];
    const float* Wv  = (const float*)d_in[3];
    const float* Wo  = (const float*)d_in[4];
    const float* bo  = (const float*)d_in[5];
    const float* W1  = (const float*)d_in[6];
    const float* b1  = (const float*)d_in[7];
    const float* W2  = (const float*)d_in[8];
    const float* b2  = (const float*)d_in[9];
    const float* g1  = (const float*)d_in[10];
    const float* be1 = (const float*)d_in[11];
    const float* g2  = (const float*)d_in[12];
    const float* be2 = (const float*)d_in[13];

    char* ws = (char*)d_ws;
    size_t off = 0;
    auto alloc = [&](size_t bytes) {
        void* p = ws + off;
        off = (off + bytes + 255) & ~(size_t)255;
        return p;
    };
    bf16*  xn    = (bf16*)alloc((size_t)BT * DIM * 2);   // LN output (reused for both LNs)
    bf16*  qkvb  = (bf16*)alloc((size_t)BT * 216 * 2);
    bf16*  o_pad = (bf16*)alloc((size_t)BT * 96 * 2);
    float* x1    = (float*)alloc((size_t)BT * DIM * 4);  // residual stream after attention, fp32
    bf16*  ffb   = (bf16*)alloc((size_t)BT * DFF * 2);
    bf16*  wqkv  = (bf16*)alloc((size_t)216 * 768 * 2);
    bf16*  wo_t  = (bf16*)alloc((size_t)768 * 96 * 2);
    bf16*  w1t   = (bf16*)alloc((size_t)3072 * 768 * 2);
    bf16*  w2t   = (bf16*)alloc((size_t)768 * 3072 * 2);

    const int PACK_N = 216 * 768 + 768 * 96 + 3072 * 768 + 768 * 3072;
    pack_kernel<<<(PACK_N + 255) / 256, 256, 0, stream>>>(Wq, Wk, Wv, Wo, W1, W2,
                                                          wqkv, wo_t, w1t, w2t);
    ln_kernel<<<BT, 256, 0, stream>>>(x, g1, be1, xn);
    gemm_kernel<false, false, false, bf16><<<dim3(128, 2), 256, 0, stream>>>(
        xn, wqkv, nullptr, nullptr, qkvb, BT, 216, 768);
    attn_kernel<<<32 * NH * 2, 256, 0, stream>>>(qkvb, o_pad);
    gemm_kernel<false, true, true, float><<<dim3(128, 6), 256, 0, stream>>>(
        o_pad, wo_t, bo, x, x1, BT, 768, 96);
    ln_kernel<<<BT, 256, 0, stream>>>(x1, g2, be2, xn);
    gemm_kernel<true, true, false, bf16><<<dim3(128, 24), 256, 0, stream>>>(
        xn, w1t, b1, nullptr, ffb, BT, 3072, 768);
    gemm_kernel<false, true, true, float><<<dim3(128, 6), 256, 0, stream>>>(
        ffb, w2t, b2, x1, (float*)d_out, BT, 768, 3072);
}

// Round 3
// 505.228 us; speedup vs baseline: 1.0971x; 1.0971x over previous
//
#include <hip/hip_runtime.h>
#include <hip/hip_bf16.h>

#define BT 16384   // B*T = 32*512
#define DIM 768
#define NH 12
#define DFF 3072

typedef __attribute__((ext_vector_type(8))) short short8;
typedef __attribute__((ext_vector_type(4))) float floatx4;

using bf16 = __hip_bfloat16;

static __device__ __forceinline__ float b2f(bf16 v) { return __bfloat162float(v); }
static __device__ __forceinline__ bf16 f2b(float v) { return __float2bfloat16(v); }
static __device__ __forceinline__ void st_o(bf16* p, float v) { *p = __float2bfloat16(v); }
static __device__ __forceinline__ void st_o(float* p, float v) { *p = v; }

// async global->LDS DMA, 16B per lane; LDS dest is wave-uniform base + lane*16
static __device__ __forceinline__ void gload_lds16(const void* g, void* l) {
    __builtin_amdgcn_global_load_lds(
        (const __attribute__((address_space(1))) unsigned int*)g,
        (__attribute__((address_space(3))) unsigned int*)l, 16, 0, 0);
}

// ---- small pack: wqkv [256][768] (rows>=216 zero), wo_t [768][96] (k>=72 zero) ----
__global__ __launch_bounds__(256) void pack_small_kernel(
    const float* __restrict__ Wq, const float* __restrict__ Wk, const float* __restrict__ Wv,
    const float* __restrict__ Wo, bf16* __restrict__ wqkv, bf16* __restrict__ wo_t)
{
    int i = blockIdx.x * 256 + threadIdx.x;
    const int S0 = 256 * 768, S1 = 768 * 96;
    if (i < S0) {
        int c = i / 768, dd = i % 768;           // row c (output col), k = dd
        float v = 0.f;
        if (c < 216) {
            int sel = c / 72, cc = c % 72, h = cc / 6, e = cc % 6;
            const float* W = (sel == 0) ? Wq : (sel == 1) ? Wk : Wv;   // (H, D, E)
            v = W[((size_t)h * 768 + dd) * 6 + e];
        }
        wqkv[i] = f2b(v);
    } else if ((i -= S0) < S1) {
        int n = i / 96, r = i % 96;              // Wo is (72, 768): [r][n]
        wo_t[i] = f2b(r < 72 ? Wo[r * 768 + n] : 0.f);
    }
}

// ---- tiled transpose: in fp32 [R][C] -> out bf16 [C][R]; grid (C/32, R/32), 256 thr ----
__global__ __launch_bounds__(256) void transpose_kernel(
    const float* __restrict__ in, bf16* __restrict__ out, int R, int C)
{
    __shared__ float t[32][33];
    int c0 = blockIdx.x * 32, r0 = blockIdx.y * 32;
    int cx = threadIdx.x & 31, ry = threadIdx.x >> 5;   // ry 0..7
#pragma unroll
    for (int j = 0; j < 4; j++)
        t[ry + j * 8][cx] = in[(size_t)(r0 + ry + j * 8) * C + c0 + cx];
    __syncthreads();
    int rx = cx, cy = ry;
#pragma unroll
    for (int j = 0; j < 4; j++)
        out[(size_t)(c0 + cy + j * 8) * R + r0 + rx] = f2b(t[rx][cy + j * 8]);
}

// ---------------- LayerNorm: one block per row of 768, fp32 in, bf16 out ----------------
__global__ __launch_bounds__(256) void ln_kernel(
    const float* __restrict__ x, const float* __restrict__ g, const float* __restrict__ be,
    bf16* __restrict__ out)
{
    int row = blockIdx.x;
    int tid = threadIdx.x;
    const float* xr = x + (size_t)row * DIM;
    float v[3], s = 0.f, s2 = 0.f;
#pragma unroll
    for (int i = 0; i < 3; i++) {
        float t = xr[tid + i * 256];
        v[i] = t; s += t; s2 += t * t;
    }
#pragma unroll
    for (int off = 32; off; off >>= 1) {
        s += __shfl_down(s, off);
        s2 += __shfl_down(s2, off);
    }
    __shared__ float red[8];
    int wv = tid >> 6, ln = tid & 63;
    if (ln == 0) { red[wv] = s; red[4 + wv] = s2; }
    __syncthreads();
    float ts = red[0] + red[1] + red[2] + red[3];
    float ts2 = red[4] + red[5] + red[6] + red[7];
    float mean = ts * (1.f / 768.f);
    float var = ts2 * (1.f / 768.f) - mean * mean;
    float rstd = rsqrtf(var + 1e-5f);
    bf16* orow = out + (size_t)row * DIM;
#pragma unroll
    for (int i = 0; i < 3; i++) {
        int dcol = tid + i * 256;
        orow[dcol] = f2b((v[i] - mean) * rstd * g[dcol] + be[dcol]);
    }
}

// ---------------- MFMA bf16 GEMM: C[M,N] = A[M,K] @ Bt[N,K]^T (+bias)(+res)(+relu) ----------------
// 128x128 tile, BK=32, 256 threads (4 waves, 2x2 of 64x64), 16x16x32 bf16 MFMA.
// Staging via global_load_lds (16B/lane), unpadded LDS stride 32 (uniform 8/bank -> conflict-free).
// Requires: M%128==0, K%32==0, Bt allocated/zero-padded to ceil(N/128)*128 rows.
// A frag: lane holds A[m=lane&15][k=quad*8+j]; B frag: Bt[n=lane&15][k=quad*8+j];
// C/D: col=lane&15, row=quad*4+reg.
template <bool RELU, bool BIAS, bool RES, typename OutT>
__global__ __launch_bounds__(256) void gemm_kernel(
    const bf16* __restrict__ A, const bf16* __restrict__ Bt,
    const float* __restrict__ bias, const float* __restrict__ res,
    OutT* __restrict__ C, int M, int N, int K)
{
    __shared__ __align__(16) bf16 lA[128 * 32];
    __shared__ __align__(16) bf16 lB[128 * 32];
    const int tid = threadIdx.x;
    const int bm = blockIdx.x * 128;
    const int bn = blockIdx.y * 128;
    const int wave = tid >> 6, lane = tid & 63;
    const int wm = (wave >> 1) * 64, wn = (wave & 1) * 64;
    const int quad = lane >> 4, l16 = lane & 15;
    const int lrow = lane >> 2;          // 0..15: row within 16-row DMA slab
    const int lkc = (lane & 3) * 8;      // 0,8,16,24: k offset within slab

    floatx4 acc[4][4] = {};

    for (int k0 = 0; k0 < K; k0 += 32) {
        // each wave DMAs two 16-row slabs of A and of B (lane i lands at base+i*16B)
#pragma unroll
        for (int it = 0; it < 2; it++) {
            int r = wave * 32 + it * 16;
            gload_lds16(A + (size_t)(bm + r + lrow) * K + k0 + lkc, lA + r * 32);
            gload_lds16(Bt + (size_t)(bn + r + lrow) * K + k0 + lkc, lB + r * 32);
        }
        __syncthreads();   // drains vmcnt (compiler emits full waitcnt before s_barrier)
        short8 af[4], bfr[4];
#pragma unroll
        for (int mt = 0; mt < 4; mt++)
            af[mt] = *(const short8*)(lA + (wm + mt * 16 + l16) * 32 + quad * 8);
#pragma unroll
        for (int nt = 0; nt < 4; nt++)
            bfr[nt] = *(const short8*)(lB + (wn + nt * 16 + l16) * 32 + quad * 8);
#pragma unroll
        for (int mt = 0; mt < 4; mt++)
#pragma unroll
            for (int nt = 0; nt < 4; nt++)
                acc[mt][nt] = __builtin_amdgcn_mfma_f32_16x16x32_bf16(af[mt], bfr[nt], acc[mt][nt], 0, 0, 0);
        __syncthreads();
    }

#pragma unroll
    for (int mt = 0; mt < 4; mt++) {
#pragma unroll
        for (int nt = 0; nt < 4; nt++) {
            int gc = bn + wn + nt * 16 + l16;
            if (gc < N) {
#pragma unroll
                for (int r = 0; r < 4; r++) {
                    int gr = bm + wm + mt * 16 + quad * 4 + r;
                    float v0 = acc[mt][nt][r];
                    if constexpr (BIAS) v0 += bias[gc];
                    if constexpr (RES) v0 += res[(size_t)gr * N + gc];
                    if constexpr (RELU) v0 = fmaxf(v0, 0.f);
                    st_o(C + (size_t)gr * N + gc, v0);
                }
            }
        }
    }
}

// ---------------- causal attention, online softmax; qkv layout [BT][216]: q|k|v each 72 cols ----------------
__global__ __launch_bounds__(256) void attn_kernel(const bf16* __restrict__ qkv, bf16* __restrict__ o_pad)
{
    int blk = blockIdx.x;
    int half = blk & 1;
    int bh = blk >> 1;
    int b = bh / NH, h = bh % NH;
    int t0 = half * 256;
    int smax = t0 + 256;

    __shared__ float ks[512 * 6];
    __shared__ float vs[512 * 6];
    const bf16* base = qkv + (size_t)b * 512 * 216;
    for (int i = threadIdx.x; i < smax * 6; i += 256) {
        int s = i / 6, e = i % 6;
        ks[i] = b2f(base[s * 216 + 72 + h * 6 + e]);
        vs[i] = b2f(base[s * 216 + 144 + h * 6 + e]);
    }
    __syncthreads();

    int t = t0 + threadIdx.x;
    float q0 = b2f(base[t * 216 + h * 6 + 0]);
    float q1 = b2f(base[t * 216 + h * 6 + 1]);
    float q2 = b2f(base[t * 216 + h * 6 + 2]);
    float q3 = b2f(base[t * 216 + h * 6 + 3]);
    float q4 = b2f(base[t * 216 + h * 6 + 4]);
    float q5 = b2f(base[t * 216 + h * 6 + 5]);

    const float scale = 0.4082482904638630f;  // 1/sqrt(6)
    float m = -1e30f, l = 0.f;
    float o0 = 0, o1 = 0, o2 = 0, o3 = 0, o4 = 0, o5 = 0;
    for (int s = 0; s <= t; s++) {
        const float* kk = &ks[s * 6];
        float sc = (q0 * kk[0] + q1 * kk[1] + q2 * kk[2] + q3 * kk[3] + q4 * kk[4] + q5 * kk[5]) * scale;
        float nm = fmaxf(m, sc);
        float alpha = __expf(m - nm);
        float p = __expf(sc - nm);
        l = l * alpha + p;
        const float* vv = &vs[s * 6];
        o0 = o0 * alpha + p * vv[0];
        o1 = o1 * alpha + p * vv[1];
        o2 = o2 * alpha + p * vv[2];
        o3 = o3 * alpha + p * vv[3];
        o4 = o4 * alpha + p * vv[4];
        o5 = o5 * alpha + p * vv[5];
        m = nm;
    }
    float inv = 1.f / l;
    bf16* orow = o_pad + (size_t)(b * 512 + t) * 96 + h * 6;
    orow[0] = f2b(o0 * inv);
    orow[1] = f2b(o1 * inv);
    orow[2] = f2b(o2 * inv);
    orow[3] = f2b(o3 * inv);
    orow[4] = f2b(o4 * inv);
    orow[5] = f2b(o5 * inv);
    // cols 72..95 of o_pad stay poison (finite bf16): matching wo_t k-cols are zero -> contributes 0.
}

extern "C" void kernel_launch(void* const* d_in, const int* in_sizes, int n_in,
                              void* d_out, int out_size, void* d_ws, size_t ws_size,
                              hipStream_t stream)
{
    const float* x   = (const float*)d_in[0];
    const float* Wq  = (const float*)d_in[1];
    const float* Wk  = (const float*)d_in[2];
    const float* Wv  = (const float*)d_in[3];
    const float* Wo  = (const float*)d_in[4];
    const float* bo  = (const float*)d_in[5];
    const float* W1  = (const float*)d_in[6];
    const float* b1  = (const float*)d_in[7];
    const float* W2  = (const float*)d_in[8];
    const float* b2  = (const float*)d_in[9];
    const float* g1  = (const float*)d_in[10];
    const float* be1 = (const float*)d_in[11];
    const float* g2  = (const float*)d_in[12];
    const float* be2 = (const float*)d_in[13];

    char* ws = (char*)d_ws;
    size_t off = 0;
    auto alloc = [&](size_t bytes) {
        void* p = ws + off;
        off = (off + bytes + 255) & ~(size_t)255;
        return p;
    };
    bf16*  xn    = (bf16*)alloc((size_t)BT * DIM * 2);   // LN output (reused for both LNs)
    bf16*  qkvb  = (bf16*)alloc((size_t)BT * 216 * 2);
    bf16*  o_pad = (bf16*)alloc((size_t)BT * 96 * 2);
    float* x1    = (float*)alloc((size_t)BT * DIM * 4);  // residual stream after attention, fp32
    bf16*  ffb   = (bf16*)alloc((size_t)BT * DFF * 2);
    bf16*  wqkv  = (bf16*)alloc((size_t)256 * 768 * 2);  // padded to 256 rows (zeros)
    bf16*  wo_t  = (bf16*)alloc((size_t)768 * 96 * 2);
    bf16*  w1t   = (bf16*)alloc((size_t)3072 * 768 * 2);
    bf16*  w2t   = (bf16*)alloc((size_t)768 * 3072 * 2);

    const int PACK_N = 256 * 768 + 768 * 96;
    pack_small_kernel<<<(PACK_N + 255) / 256, 256, 0, stream>>>(Wq, Wk, Wv, Wo, wqkv, wo_t);
    transpose_kernel<<<dim3(3072 / 32, 768 / 32), 256, 0, stream>>>(W1, w1t, 768, 3072);
    transpose_kernel<<<dim3(768 / 32, 3072 / 32), 256, 0, stream>>>(W2, w2t, 3072, 768);

    ln_kernel<<<BT, 256, 0, stream>>>(x, g1, be1, xn);
    gemm_kernel<false, false, false, bf16><<<dim3(128, 2), 256, 0, stream>>>(
        xn, wqkv, nullptr, nullptr, qkvb, BT, 216, 768);
    attn_kernel<<<32 * NH * 2, 256, 0, stream>>>(qkvb, o_pad);
    gemm_kernel<false, true, true, float><<<dim3(128, 6), 256, 0, stream>>>(
        o_pad, wo_t, bo, x, x1, BT, 768, 96);
    ln_kernel<<<BT, 256, 0, stream>>>(x1, g2, be2, xn);
    gemm_kernel<true, true, false, bf16><<<dim3(128, 24), 256, 0, stream>>>(
        xn, w1t, b1, nullptr, ffb, BT, 3072, 768);
    gemm_kernel<false, true, true, float><<<dim3(128, 6), 256, 0, stream>>>(
        ffb, w2t, b2, x1, (float*)d_out, BT, 768, 3072);
}

// Round 4
// 458.085 us; speedup vs baseline: 1.2100x; 1.1029x over previous
//
#include <hip/hip_runtime.h>
#include <hip/hip_bf16.h>

#define BT 16384   // B*T = 32*512
#define DIM 768
#define NH 12
#define DFF 3072

typedef __attribute__((ext_vector_type(8))) short short8;
typedef __attribute__((ext_vector_type(4))) float floatx4;
typedef __attribute__((ext_vector_type(4))) unsigned short ushort4b;

using bf16 = __hip_bfloat16;

static __device__ __forceinline__ float b2f(bf16 v) { return __bfloat162float(v); }
static __device__ __forceinline__ bf16 f2b(float v) { return __float2bfloat16(v); }

// async global->LDS DMA, 16B per lane; LDS dest is wave-uniform base + lane*16
static __device__ __forceinline__ void gload_lds16(const void* g, void* l) {
    __builtin_amdgcn_global_load_lds(
        (const __attribute__((address_space(1))) unsigned int*)g,
        (__attribute__((address_space(3))) unsigned int*)l, 16, 0, 0);
}

// ---- small pack: wqkv [256][768] (rows>=216 zero), wo_t [768][96] (k>=72 zero) ----
__global__ __launch_bounds__(256) void pack_small_kernel(
    const float* __restrict__ Wq, const float* __restrict__ Wk, const float* __restrict__ Wv,
    const float* __restrict__ Wo, bf16* __restrict__ wqkv, bf16* __restrict__ wo_t)
{
    int i = blockIdx.x * 256 + threadIdx.x;
    const int S0 = 256 * 768, S1 = 768 * 96;
    if (i < S0) {
        int c = i / 768, dd = i % 768;
        float v = 0.f;
        if (c < 216) {
            int sel = c / 72, cc = c % 72, h = cc / 6, e = cc % 6;
            const float* W = (sel == 0) ? Wq : (sel == 1) ? Wk : Wv;   // (H, D, E)
            v = W[((size_t)h * 768 + dd) * 6 + e];
        }
        wqkv[i] = f2b(v);
    } else if ((i -= S0) < S1) {
        int n = i / 96, r = i % 96;              // Wo is (72, 768): [r][n]
        wo_t[i] = f2b(r < 72 ? Wo[r * 768 + n] : 0.f);
    }
}

// ---- tiled transpose: in fp32 [R][C] -> out bf16 [C][R]; grid (C/32, R/32), 256 thr ----
__global__ __launch_bounds__(256) void transpose_kernel(
    const float* __restrict__ in, bf16* __restrict__ out, int R, int C)
{
    __shared__ float t[32][33];
    int c0 = blockIdx.x * 32, r0 = blockIdx.y * 32;
    int cx = threadIdx.x & 31, ry = threadIdx.x >> 5;   // ry 0..7
#pragma unroll
    for (int j = 0; j < 4; j++)
        t[ry + j * 8][cx] = in[(size_t)(r0 + ry + j * 8) * C + c0 + cx];
    __syncthreads();
    int rx = cx, cy = ry;
#pragma unroll
    for (int j = 0; j < 4; j++)
        out[(size_t)(c0 + cy + j * 8) * R + r0 + rx] = f2b(t[rx][cy + j * 8]);
}

// ---------------- LayerNorm: 192 threads, float4 loads, 8B packed bf16 stores ----------------
__global__ __launch_bounds__(192) void ln_kernel(
    const float* __restrict__ x, const float* __restrict__ g, const float* __restrict__ be,
    bf16* __restrict__ out)
{
    int row = blockIdx.x;
    int tid = threadIdx.x;
    const float4* xr = (const float4*)(x + (size_t)row * DIM);
    float4 v = xr[tid];
    float s = v.x + v.y + v.z + v.w;
    float s2 = v.x * v.x + v.y * v.y + v.z * v.z + v.w * v.w;
#pragma unroll
    for (int off = 32; off; off >>= 1) {
        s += __shfl_down(s, off);
        s2 += __shfl_down(s2, off);
    }
    __shared__ float red[6];
    int wv = tid >> 6, ln = tid & 63;
    if (ln == 0) { red[wv] = s; red[3 + wv] = s2; }
    __syncthreads();
    float ts = red[0] + red[1] + red[2];
    float ts2 = red[3] + red[4] + red[5];
    float mean = ts * (1.f / 768.f);
    float var = ts2 * (1.f / 768.f) - mean * mean;
    float rstd = rsqrtf(var + 1e-5f);
    int c = tid * 4;
    float o0 = (v.x - mean) * rstd * g[c + 0] + be[c + 0];
    float o1 = (v.y - mean) * rstd * g[c + 1] + be[c + 1];
    float o2 = (v.z - mean) * rstd * g[c + 2] + be[c + 2];
    float o3 = (v.w - mean) * rstd * g[c + 3] + be[c + 3];
    bf16 h0 = f2b(o0), h1 = f2b(o1), h2 = f2b(o2), h3 = f2b(o3);
    ushort4b pk;
    pk[0] = *(unsigned short*)&h0; pk[1] = *(unsigned short*)&h1;
    pk[2] = *(unsigned short*)&h2; pk[3] = *(unsigned short*)&h3;
    *(ushort4b*)(out + (size_t)row * DIM + c) = pk;
}

// ---------------- MFMA bf16 GEMM: C[M,N] = A[M,K] @ Bt[N,K]^T (+bias)(+res)(+relu) ----------------
// 128x128 tile, K-step = NSLAB*32 (two BK=32 slabs per barrier pair keeps the conflict-free
// stride-32 LDS pattern), 256 threads (4 waves, 2x2 of 64x64), 16x16x32 bf16 MFMA.
// Staging via global_load_lds (16B/lane). Requires: M%128==0, K%(NSLAB*32)==0,
// Bt zero-padded to ceil(N/128)*128 rows, N%8==0.
// BF16OUT: epilogue via LDS tile (stride 136) -> dwordx4 stores.
template <int NSLAB, bool RELU, bool BIAS, bool RES, bool BF16OUT>
__global__ __launch_bounds__(256) void gemm_kernel(
    const bf16* __restrict__ A, const bf16* __restrict__ Bt,
    const float* __restrict__ bias, const float* __restrict__ res,
    void* __restrict__ Cv, int M, int N, int K)
{
    constexpr int SMEM_BYTES = BF16OUT ? (128 * 136 * 2) : (NSLAB * 2 * 128 * 32 * 2);
    __shared__ __align__(16) char smem[SMEM_BYTES];
    bf16* lA = (bf16*)smem;                       // [NSLAB][128][32]
    bf16* lB = lA + NSLAB * 128 * 32;

    const int tid = threadIdx.x;
    const int bm = blockIdx.x * 128;
    const int bn = blockIdx.y * 128;
    const int wave = tid >> 6, lane = tid & 63;
    const int wm = (wave >> 1) * 64, wn = (wave & 1) * 64;
    const int quad = lane >> 4, l16 = lane & 15;
    const int lrow = lane >> 2;          // 0..15: row within 16-row DMA slab
    const int lkc = (lane & 3) * 8;      // 0,8,16,24: k offset within slab

    floatx4 acc[4][4] = {};

    for (int k0 = 0; k0 < K; k0 += NSLAB * 32) {
#pragma unroll
        for (int s = 0; s < NSLAB; s++) {
#pragma unroll
            for (int it = 0; it < 2; it++) {
                int r = wave * 32 + it * 16;
                gload_lds16(A + (size_t)(bm + r + lrow) * K + k0 + s * 32 + lkc,
                            lA + s * 4096 + r * 32);
                gload_lds16(Bt + (size_t)(bn + r + lrow) * K + k0 + s * 32 + lkc,
                            lB + s * 4096 + r * 32);
            }
        }
        __syncthreads();
#pragma unroll
        for (int s = 0; s < NSLAB; s++) {
            short8 af[4], bfr[4];
#pragma unroll
            for (int mt = 0; mt < 4; mt++)
                af[mt] = *(const short8*)(lA + s * 4096 + (wm + mt * 16 + l16) * 32 + quad * 8);
#pragma unroll
            for (int nt = 0; nt < 4; nt++)
                bfr[nt] = *(const short8*)(lB + s * 4096 + (wn + nt * 16 + l16) * 32 + quad * 8);
#pragma unroll
            for (int mt = 0; mt < 4; mt++)
#pragma unroll
                for (int nt = 0; nt < 4; nt++)
                    acc[mt][nt] = __builtin_amdgcn_mfma_f32_16x16x32_bf16(af[mt], bfr[nt], acc[mt][nt], 0, 0, 0);
        }
        __syncthreads();
    }

    if constexpr (BF16OUT) {
        // acc -> LDS bf16 tile [128][136] -> cooperative dwordx4 stores
        bf16* ltile = (bf16*)smem;   // safe: loop ended with __syncthreads()
#pragma unroll
        for (int mt = 0; mt < 4; mt++) {
#pragma unroll
            for (int nt = 0; nt < 4; nt++) {
                int tc = wn + nt * 16 + l16;
#pragma unroll
                for (int r = 0; r < 4; r++) {
                    int tr = wm + mt * 16 + quad * 4 + r;
                    float v0 = acc[mt][nt][r];
                    if constexpr (BIAS) v0 += bias[bn + tc];
                    if constexpr (RELU) v0 = fmaxf(v0, 0.f);
                    ltile[tr * 136 + tc] = f2b(v0);
                }
            }
        }
        __syncthreads();
        bf16* C = (bf16*)Cv;
        int rr0 = tid >> 4, col8 = (tid & 15) * 8;
        int gc = bn + col8;
#pragma unroll
        for (int p = 0; p < 8; p++) {
            int rr = p * 16 + rr0;
            if (gc < N)
                *(short8*)(C + (size_t)(bm + rr) * N + gc) =
                    *(const short8*)(ltile + rr * 136 + col8);
        }
    } else {
        float* C = (float*)Cv;
#pragma unroll
        for (int mt = 0; mt < 4; mt++) {
#pragma unroll
            for (int nt = 0; nt < 4; nt++) {
                int gc = bn + wn + nt * 16 + l16;
                if (gc < N) {
#pragma unroll
                    for (int r = 0; r < 4; r++) {
                        int gr = bm + wm + mt * 16 + quad * 4 + r;
                        float v0 = acc[mt][nt][r];
                        if constexpr (BIAS) v0 += bias[gc];
                        if constexpr (RES) v0 += res[(size_t)gr * N + gc];
                        if constexpr (RELU) v0 = fmaxf(v0, 0.f);
                        C[(size_t)gr * N + gc] = v0;
                    }
                }
            }
        }
    }
}

// ---------------- causal attention, online softmax; qkv layout [BT][216]: q|k|v each 72 cols ----------------
// 2 blocks per (b,h); wave->t-slab remap balances work: block0 slabs {0,2,5,7}, block1 {1,3,4,6}.
__global__ __launch_bounds__(256) void attn_kernel(const bf16* __restrict__ qkv, bf16* __restrict__ o_pad)
{
    int blk = blockIdx.x;
    int half = blk & 1;
    int bh = blk >> 1;
    int b = bh / NH, h = bh % NH;
    int wave = threadIdx.x >> 6, lane = threadIdx.x & 63;
    const int jmap0[4] = {0, 2, 5, 7}, jmap1[4] = {1, 3, 4, 6};
    int j = half ? jmap1[wave] : jmap0[wave];
    int t = j * 64 + lane;
    int smax = half ? 448 : 512;

    __shared__ float ks[512 * 6];
    __shared__ float vs[512 * 6];
    const bf16* base = qkv + (size_t)b * 512 * 216;
    for (int i = threadIdx.x; i < smax * 6; i += 256) {
        int s = i / 6, e = i % 6;
        ks[i] = b2f(base[s * 216 + 72 + h * 6 + e]);
        vs[i] = b2f(base[s * 216 + 144 + h * 6 + e]);
    }
    __syncthreads();

    float q0 = b2f(base[t * 216 + h * 6 + 0]);
    float q1 = b2f(base[t * 216 + h * 6 + 1]);
    float q2 = b2f(base[t * 216 + h * 6 + 2]);
    float q3 = b2f(base[t * 216 + h * 6 + 3]);
    float q4 = b2f(base[t * 216 + h * 6 + 4]);
    float q5 = b2f(base[t * 216 + h * 6 + 5]);

    const float scale = 0.4082482904638630f;  // 1/sqrt(6)
    float m = -1e30f, l = 0.f;
    float o0 = 0, o1 = 0, o2 = 0, o3 = 0, o4 = 0, o5 = 0;
    for (int s = 0; s <= t; s++) {
        const float* kk = &ks[s * 6];
        float sc = (q0 * kk[0] + q1 * kk[1] + q2 * kk[2] + q3 * kk[3] + q4 * kk[4] + q5 * kk[5]) * scale;
        float nm = fmaxf(m, sc);
        float alpha = __expf(m - nm);
        float p = __expf(sc - nm);
        l = l * alpha + p;
        const float* vv = &vs[s * 6];
        o0 = o0 * alpha + p * vv[0];
        o1 = o1 * alpha + p * vv[1];
        o2 = o2 * alpha + p * vv[2];
        o3 = o3 * alpha + p * vv[3];
        o4 = o4 * alpha + p * vv[4];
        o5 = o5 * alpha + p * vv[5];
        m = nm;
    }
    float inv = 1.f / l;
    bf16* orow = o_pad + (size_t)(b * 512 + t) * 96 + h * 6;
    orow[0] = f2b(o0 * inv);
    orow[1] = f2b(o1 * inv);
    orow[2] = f2b(o2 * inv);
    orow[3] = f2b(o3 * inv);
    orow[4] = f2b(o4 * inv);
    orow[5] = f2b(o5 * inv);
    // cols 72..95 of o_pad stay poison (finite bf16): matching wo_t k-cols are zero -> contributes 0.
}

extern "C" void kernel_launch(void* const* d_in, const int* in_sizes, int n_in,
                              void* d_out, int out_size, void* d_ws, size_t ws_size,
                              hipStream_t stream)
{
    const float* x   = (const float*)d_in[0];
    const float* Wq  = (const float*)d_in[1];
    const float* Wk  = (const float*)d_in[2];
    const float* Wv  = (const float*)d_in[3];
    const float* Wo  = (const float*)d_in[4];
    const float* bo  = (const float*)d_in[5];
    const float* W1  = (const float*)d_in[6];
    const float* b1  = (const float*)d_in[7];
    const float* W2  = (const float*)d_in[8];
    const float* b2  = (const float*)d_in[9];
    const float* g1  = (const float*)d_in[10];
    const float* be1 = (const float*)d_in[11];
    const float* g2  = (const float*)d_in[12];
    const float* be2 = (const float*)d_in[13];

    char* ws = (char*)d_ws;
    size_t off = 0;
    auto alloc = [&](size_t bytes) {
        void* p = ws + off;
        off = (off + bytes + 255) & ~(size_t)255;
        return p;
    };
    bf16*  xn    = (bf16*)alloc((size_t)BT * DIM * 2);   // LN output (reused for both LNs)
    bf16*  qkvb  = (bf16*)alloc((size_t)BT * 216 * 2);
    bf16*  o_pad = (bf16*)alloc((size_t)BT * 96 * 2);
    float* x1    = (float*)alloc((size_t)BT * DIM * 4);  // residual stream after attention, fp32
    bf16*  ffb   = (bf16*)alloc((size_t)BT * DFF * 2);
    bf16*  wqkv  = (bf16*)alloc((size_t)256 * 768 * 2);  // padded to 256 rows (zeros)
    bf16*  wo_t  = (bf16*)alloc((size_t)768 * 96 * 2);
    bf16*  w1t   = (bf16*)alloc((size_t)3072 * 768 * 2);
    bf16*  w2t   = (bf16*)alloc((size_t)768 * 3072 * 2);

    const int PACK_N = 256 * 768 + 768 * 96;
    pack_small_kernel<<<(PACK_N + 255) / 256, 256, 0, stream>>>(Wq, Wk, Wv, Wo, wqkv, wo_t);
    transpose_kernel<<<dim3(3072 / 32, 768 / 32), 256, 0, stream>>>(W1, w1t, 768, 3072);
    transpose_kernel<<<dim3(768 / 32, 3072 / 32), 256, 0, stream>>>(W2, w2t, 3072, 768);

    ln_kernel<<<BT, 192, 0, stream>>>(x, g1, be1, xn);
    gemm_kernel<2, false, false, false, true><<<dim3(128, 2), 256, 0, stream>>>(
        xn, wqkv, nullptr, nullptr, qkvb, BT, 216, 768);
    attn_kernel<<<32 * NH * 2, 256, 0, stream>>>(qkvb, o_pad);
    gemm_kernel<1, false, true, true, false><<<dim3(128, 6), 256, 0, stream>>>(
        o_pad, wo_t, bo, x, x1, BT, 768, 96);
    ln_kernel<<<BT, 192, 0, stream>>>(x1, g2, be2, xn);
    gemm_kernel<2, true, true, false, true><<<dim3(128, 24), 256, 0, stream>>>(
        xn, w1t, b1, nullptr, ffb, BT, 3072, 768);
    gemm_kernel<2, false, true, true, false><<<dim3(128, 6), 256, 0, stream>>>(
        ffb, w2t, b2, x1, (float*)d_out, BT, 768, 3072);
}